// Round 5
// baseline (109.988 us; speedup 1.0000x reference)
//
#include <hip/hip_runtime.h>
#include <cstdint>

#define T_STEPS 2048
#define NFEAT   2048
#define A_POS 0.05f
#define A_NEG 0.05f
#define LR    0.01f
#define DECAY 0.60653065971263342f   // exp(-1/2), tau_pos == tau_neg == 2

typedef unsigned short u16;
typedef short short8 __attribute__((ext_vector_type(8)));
typedef float f32x4 __attribute__((ext_vector_type(4)));

#define AS1 __attribute__((address_space(1)))
#define AS3 __attribute__((address_space(3)))

__device__ __forceinline__ uint32_t f2bf(float f) {
  uint32_t u = __float_as_uint(f);
  return (u + 0x7FFFu + ((u >> 16) & 1u)) >> 16;   // RNE, finite values only
}
__device__ __forceinline__ uint32_t packbf2(float lo, float hi) {
  return f2bf(lo) | (f2bf(hi) << 16);
}

// ---------------------------------------------------------------------------
// Prep kernel (fused, block-range dispatch):
//  blocks [0,256):     scan -> kinT[j][t] bf16 (coalesced via swizzled LDS)
//  blocks [256,1280):  transpose -> outT[i][t] bf16
//  block  1280:        zero the 256 split-K tile flags
// ---------------------------------------------------------------------------
#define TC   64
#define HALO 48   // decay^48 = e^-24 ~ 4e-11, negligible vs bf16 rounding
__global__ __launch_bounds__(256) void prep_kernel(
    const float* __restrict__ in, const float* __restrict__ outspk,
    u16* __restrict__ kinT, u16* __restrict__ outT,
    unsigned* __restrict__ flags) {
  __shared__ union {
    float tile[64][65];   // transpose role (16.6 KB)
    u16   ldsJ[256][64];  // scan write-coalescing (32 KB)
  } sm;
  const int bx = blockIdx.x;
  const int tid = threadIdx.x;

  if (bx < 256) {
    // ---- scan role: thread owns feature column j = jb + tid ----
    const int jb = (bx & 7) * 256;
    const int j  = jb + tid;
    const int t0 = (bx >> 3) * TC;
    const float d = DECAY;

    float kv[TC];
    float f = 0.f;
    int tb = t0 - HALO; if (tb < 0) tb = 0;
    for (int t = tb; t < t0; ++t) f = d * (f + in[(size_t)t * NFEAT + j]);
#pragma unroll
    for (int u = 0; u < TC; ++u) {
      kv[u] = f;                                   // F[t0+u] (excludes in[t0+u])
      f = d * (f + in[(size_t)(t0 + u) * NFEAT + j]);
    }

    float b = 0.f;
    int te = t0 + TC - 1 + HALO; if (te > T_STEPS - 1) te = T_STEPS - 1;
    for (int t = te; t >= t0 + TC; --t) b = in[(size_t)t * NFEAT + j] + d * b;
#pragma unroll
    for (int u = TC - 1; u >= 0; --u) {
      b = in[(size_t)(t0 + u) * NFEAT + j] + d * b;  // B[t0+u] (includes t)
      kv[u] = A_POS * kv[u] - A_NEG * b;
    }

    // stage into LDS with XOR-swizzled 16B chunks, then coalesced store
    uint4* rowp = (uint4*)&sm.ldsJ[tid][0];          // this thread's 128B row
#pragma unroll
    for (int c = 0; c < 8; ++c) {
      uint4 w;
      w.x = packbf2(kv[c * 8 + 0], kv[c * 8 + 1]);
      w.y = packbf2(kv[c * 8 + 2], kv[c * 8 + 3]);
      w.z = packbf2(kv[c * 8 + 4], kv[c * 8 + 5]);
      w.w = packbf2(kv[c * 8 + 6], kv[c * 8 + 7]);
      rowp[c ^ (tid & 7)] = w;
    }
    __syncthreads();
#pragma unroll
    for (int p = 0; p < 8; ++p) {
      int jr = p * 32 + (tid >> 3);                  // LDS row / local feature
      int c  = tid & 7;                              // 16B chunk along t
      uint4 v = ((const uint4*)&sm.ldsJ[jr][0])[c ^ (jr & 7)];
      *(uint4*)&kinT[(size_t)(jb + jr) * T_STEPS + t0 + c * 8] = v;
    }
  } else if (bx < 1280) {
    // ---- transpose role ----
    const int b  = bx - 256;
    const int t0 = (b & 31) * 64;
    const int i0 = (b >> 5) * 64;
#pragma unroll
    for (int p = 0; p < 16; ++p) {
      int idx = tid + p * 256;
      int r = idx >> 6, c = idx & 63;
      sm.tile[r][c] = outspk[(size_t)(t0 + r) * NFEAT + i0 + c];
    }
    __syncthreads();
#pragma unroll
    for (int p = 0; p < 8; ++p) {
      int idx = tid + p * 256;
      int pr = idx >> 5, pc = idx & 31;
      uint32_t w = packbf2(sm.tile[2 * pc][pr], sm.tile[2 * pc + 1][pr]);
      ((uint32_t*)outT)[(size_t)(i0 + pr) * (T_STEPS / 2) + (t0 >> 1) + pc] = w;
    }
  } else {
    // ---- flag-zero role ----
    flags[tid] = 0u;
  }
}

// ---------------------------------------------------------------------------
// GEMM, split-K=2: P[kh][i][j] = sum_{k in half} A[i][k]*B[j][k]; the second
// finisher of each tile combines C = W + LR*(P0+P1).
// Tile 128x128, BK=64, 4 waves (2x2), wave-tile 64x64 (4x4 frags) -> 2x the
// FLOP per LDS byte of the previous 64x32 wave-tile. Grid 512 = 2 blocks/CU.
// T2 XOR swizzle (rule 21): inverse-swizzled global src + swizzled ds_read.
// ---------------------------------------------------------------------------
__global__ __launch_bounds__(256, 2) void stdp_gemm_kernel(
    const u16* __restrict__ A, const u16* __restrict__ B,
    const float* __restrict__ W, float* __restrict__ P,
    unsigned* __restrict__ flags, float* __restrict__ C) {
  __shared__ u16 ldsA[2][128 * 64];   // 32 KB
  __shared__ u16 ldsB[2][128 * 64];   // 32 KB
  __shared__ int sflag;
  const int tid = threadIdx.x;
  const int lane = tid & 63, wave = tid >> 6;
  const int wm = wave >> 1, wn = wave & 1;
  const int lr = lane & 15, lk = lane >> 4;

  // decode 512 blocks -> (kh, it, jt) with XCD-chunked locality
  const int bid = blockIdx.x;
  const int xcd = bid & 7, q = bid >> 3;    // q in [0,64)
  const int kh  = q >> 5;                   // K-half
  const int qq  = q & 31;
  const int it  = (xcd >> 1) * 4 + (qq >> 3);   // 0..15
  const int jt  = (xcd & 1) * 8 + (qq & 7);     // 0..15
  const int i0 = it * 128, j0 = jt * 128;
  const int kb = kh * (T_STEPS / 2);

  f32x4 acc[4][4];
#pragma unroll
  for (int m = 0; m < 4; ++m)
#pragma unroll
    for (int n = 0; n < 4; ++n) acc[m][n] = (f32x4){0.f, 0.f, 0.f, 0.f};

  // per K-step: A 128x64 + B 128x64 staged; 4+4 gload_lds per thread-slot
  auto stage = [&](int buf, int kt) {
    const int k0 = kb + kt * 64;
#pragma unroll
    for (int p = 0; p < 4; ++p) {
      int ch = p * 256 + tid;
      int r = ch >> 3, c = ch & 7;
      int csw = c ^ (r & 7);                      // inverse-swizzle the SOURCE
      __builtin_amdgcn_global_load_lds(
          (const AS1 void*)(A + (size_t)(i0 + r) * T_STEPS + k0 + csw * 8),
          (AS3 void*)((char*)&ldsA[buf][0] + (p * 256 + wave * 64) * 16),
          16, 0, 0);
    }
#pragma unroll
    for (int p = 0; p < 4; ++p) {
      int ch = p * 256 + tid;
      int r = ch >> 3, c = ch & 7;
      int csw = c ^ (r & 7);
      __builtin_amdgcn_global_load_lds(
          (const AS1 void*)(B + (size_t)(j0 + r) * T_STEPS + k0 + csw * 8),
          (AS3 void*)((char*)&ldsB[buf][0] + (p * 256 + wave * 64) * 16),
          16, 0, 0);
    }
  };

  stage(0, 0);
  asm volatile("s_waitcnt vmcnt(0)" ::: "memory");
  __syncthreads();

  int cur = 0;
  const int NKT = (T_STEPS / 2) / 64;   // 16
  for (int kt = 0; kt < NKT; ++kt) {
    if (kt + 1 < NKT) stage(cur ^ 1, kt + 1);  // prefetch next tile
#pragma unroll
    for (int ks = 0; ks < 2; ++ks) {
      short8 af[4], bf4[4];
#pragma unroll
      for (int m = 0; m < 4; ++m) {
        int row = wm * 64 + m * 16 + lr;
        int g = (ks * 4 + lk) ^ (row & 7);       // swizzled read
        af[m] = *(const short8*)((const char*)&ldsA[cur][0] + row * 128 + g * 16);
      }
#pragma unroll
      for (int n = 0; n < 4; ++n) {
        int row = wn * 64 + n * 16 + lr;
        int g = (ks * 4 + lk) ^ (row & 7);
        bf4[n] = *(const short8*)((const char*)&ldsB[cur][0] + row * 128 + g * 16);
      }
#pragma unroll
      for (int m = 0; m < 4; ++m)
#pragma unroll
        for (int n = 0; n < 4; ++n)
          acc[m][n] = __builtin_amdgcn_mfma_f32_16x16x32_bf16(af[m], bf4[n], acc[m][n], 0, 0, 0);
    }
    __syncthreads();  // prefetch landed + reads done
    cur ^= 1;
  }

  // write this half's partial (C/D layout: col=lane&15, row=(lane>>4)*4+r)
  float* myP = P + (size_t)kh * NFEAT * NFEAT;
#pragma unroll
  for (int m = 0; m < 4; ++m)
#pragma unroll
    for (int n = 0; n < 4; ++n) {
      int col = j0 + wn * 64 + n * 16 + lr;
#pragma unroll
      for (int r = 0; r < 4; ++r) {
        int row = i0 + wm * 64 + m * 16 + lk * 4 + r;
        myP[(size_t)row * NFEAT + col] = acc[m][n][r];
      }
    }

  __syncthreads();                 // all of this block's P stores issued
  if (tid == 0) {
    __threadfence();               // release: P visible device-wide
    unsigned old = atomicAdd(&flags[it * 16 + jt], 1u);
    sflag = (old == 1);            // second finisher combines
  }
  __syncthreads();
  if (sflag) {
    __threadfence();               // acquire: partner's P visible
    const float* P0 = P;
    const float* P1 = P + (size_t)NFEAT * NFEAT;
#pragma unroll
    for (int p = 0; p < 16; ++p) {
      int idx = p * 256 + tid;                   // 0..4095
      int row = i0 + (idx >> 5);
      int c0  = j0 + (idx & 31) * 4;
      size_t off = (size_t)row * NFEAT + c0;
      float4 a = *(const float4*)&P0[off];
      float4 b = *(const float4*)&P1[off];
      float4 w = *(const float4*)&W[off];
      float4 o;
      o.x = w.x + LR * (a.x + b.x);
      o.y = w.y + LR * (a.y + b.y);
      o.z = w.z + LR * (a.z + b.z);
      o.w = w.w + LR * (a.w + b.w);
      *(float4*)&C[off] = o;
    }
  }
}

extern "C" void kernel_launch(void* const* d_in, const int* in_sizes, int n_in,
                              void* d_out, int out_size, void* d_ws, size_t ws_size,
                              hipStream_t stream) {
  const float* weight  = (const float*)d_in[0];
  const float* in_spk  = (const float*)d_in[1];
  const float* out_spk = (const float*)d_in[2];
  float* out = (float*)d_out;

  u16* kinT = (u16*)d_ws;                                   // 8 MB bf16 [I][T]
  u16* outT = kinT + (size_t)T_STEPS * NFEAT;               // 8 MB bf16 [O][T]
  float* P = (float*)((char*)d_ws + (size_t)16 * 1024 * 1024);      // 32 MB
  unsigned* flags = (unsigned*)((char*)d_ws + (size_t)48 * 1024 * 1024); // 1 KB

  prep_kernel<<<dim3(1281), 256, 0, stream>>>(in_spk, out_spk, kinT, outT, flags);

  stdp_gemm_kernel<<<dim3(512), 256, 0, stream>>>(outT, kinT, weight, P, flags, out);
}

// Round 6
// 37.690 us; speedup vs baseline: 2.9182x; 2.9182x over previous
//
#include <hip/hip_runtime.h>
#include <cstdint>

#define T_STEPS 2048
#define NFEAT   2048
#define A_POS 0.05f
#define A_NEG 0.05f
#define LR    0.01f
#define DECAY 0.60653065971263342f   // exp(-1/2), tau_pos == tau_neg == 2
#define QSCALE 1000.0f               // |kin| <= 0.12707 -> |q| <= 127 (fits i8)
#define OUTSCALE 1.0e-5f             // LR / QSCALE

typedef unsigned char u8;
typedef int i32x4 __attribute__((ext_vector_type(4)));

#define AS1 __attribute__((address_space(1)))
#define AS3 __attribute__((address_space(3)))

__device__ __forceinline__ uint32_t q8(float a, float b, float c, float d) {
  int qa = __float2int_rn(a * QSCALE) & 255;
  int qb = __float2int_rn(b * QSCALE) & 255;
  int qc = __float2int_rn(c * QSCALE) & 255;
  int qd = __float2int_rn(d * QSCALE) & 255;
  return (uint32_t)(qa | (qb << 8) | (qc << 16) | (qd << 24));
}
__device__ __forceinline__ uint32_t s8(float a, float b, float c, float d) {
  return (uint32_t)(__float2int_rn(a) | (__float2int_rn(b) << 8) |
                    (__float2int_rn(c) << 16) | (__float2int_rn(d) << 24));
}

// ---------------------------------------------------------------------------
// Prep (block-range dispatch):
//  blocks [0,256):     STDP scans -> kinT[j][t] i8 (fixed-point, x1000)
//  blocks [256,1280):  transpose  -> outT[i][t] i8 (binary, exact)
// ---------------------------------------------------------------------------
#define TC   64
#define HALO 32   // decay^32 = 1.1e-7 -> truncation ~1.4e-8 << i8 quantum 5e-4
__global__ __launch_bounds__(256) void prep_kernel(
    const float* __restrict__ in, const float* __restrict__ outspk,
    u8* __restrict__ kinT, u8* __restrict__ outT) {
  __shared__ union {
    float tile[64][65];   // transpose role
    u8    ldsJ[256][64];  // scan write-coalescing
  } sm;
  const int bx = blockIdx.x;
  const int tid = threadIdx.x;

  if (bx < 256) {
    // ---- scan role: thread owns feature column j ----
    const int jb = (bx & 7) * 256;
    const int j  = jb + tid;
    const int t0 = (bx >> 3) * TC;
    const float d = DECAY;

    float kv[TC];
    float f = 0.f;
    int tb = t0 - HALO; if (tb < 0) tb = 0;
    for (int t = tb; t < t0; ++t) f = d * (f + in[(size_t)t * NFEAT + j]);
#pragma unroll
    for (int u = 0; u < TC; ++u) {
      kv[u] = f;                                   // F[t0+u] (excludes in[t0+u])
      f = d * (f + in[(size_t)(t0 + u) * NFEAT + j]);
    }

    float b = 0.f;
    int te = t0 + TC - 1 + HALO; if (te > T_STEPS - 1) te = T_STEPS - 1;
    for (int t = te; t >= t0 + TC; --t) b = in[(size_t)t * NFEAT + j] + d * b;
#pragma unroll
    for (int u = TC - 1; u >= 0; --u) {
      b = in[(size_t)(t0 + u) * NFEAT + j] + d * b;  // B[t0+u] (includes t)
      kv[u] = A_POS * kv[u] - A_NEG * b;
    }

    // quantize to i8 and stage into LDS (chunk-XOR swizzle), then coalesced out
    uint4* rowp = (uint4*)&sm.ldsJ[tid][0];          // 64 B row = 4 x 16B
#pragma unroll
    for (int c = 0; c < 4; ++c) {
      uint4 w;
      w.x = q8(kv[c*16+ 0], kv[c*16+ 1], kv[c*16+ 2], kv[c*16+ 3]);
      w.y = q8(kv[c*16+ 4], kv[c*16+ 5], kv[c*16+ 6], kv[c*16+ 7]);
      w.z = q8(kv[c*16+ 8], kv[c*16+ 9], kv[c*16+10], kv[c*16+11]);
      w.w = q8(kv[c*16+12], kv[c*16+13], kv[c*16+14], kv[c*16+15]);
      rowp[c ^ (tid & 3)] = w;
    }
    __syncthreads();
#pragma unroll
    for (int p = 0; p < 4; ++p) {
      int jr = p * 64 + (tid >> 2);                  // local feature row
      int c  = tid & 3;                              // 16B chunk along t
      uint4 v = ((const uint4*)&sm.ldsJ[jr][0])[c ^ (jr & 3)];
      *(uint4*)&kinT[(size_t)(jb + jr) * T_STEPS + t0 + c * 16] = v;
    }
  } else {
    // ---- transpose role: out_spk [t][i] fp32 -> outT [i][t] i8 ----
    const int bb = bx - 256;
    const int t0 = (bb & 31) * 64;
    const int i0 = (bb >> 5) * 64;
#pragma unroll
    for (int p = 0; p < 16; ++p) {
      int idx = tid + p * 256;
      int r = idx >> 6, c = idx & 63;
      sm.tile[r][c] = outspk[(size_t)(t0 + r) * NFEAT + i0 + c];
    }
    __syncthreads();
    const int il = tid >> 2, tc = tid & 3;           // thread: 16 t for one i
    uint4 w;
    w.x = s8(sm.tile[tc*16+ 0][il], sm.tile[tc*16+ 1][il], sm.tile[tc*16+ 2][il], sm.tile[tc*16+ 3][il]);
    w.y = s8(sm.tile[tc*16+ 4][il], sm.tile[tc*16+ 5][il], sm.tile[tc*16+ 6][il], sm.tile[tc*16+ 7][il]);
    w.z = s8(sm.tile[tc*16+ 8][il], sm.tile[tc*16+ 9][il], sm.tile[tc*16+10][il], sm.tile[tc*16+11][il]);
    w.w = s8(sm.tile[tc*16+12][il], sm.tile[tc*16+13][il], sm.tile[tc*16+14][il], sm.tile[tc*16+15][il]);
    *(uint4*)&outT[(size_t)(i0 + il) * T_STEPS + t0 + tc * 16] = w;
  }
}

// ---------------------------------------------------------------------------
// i8 GEMM: C[i][j] = W[i][j] + 1e-5 * sum_k A[i][k]*B[j][k]   (i32 exact acc)
// A = outT i8 (binary), B = kinT i8 (kin x1000). Tile 128x128, BK=128,
// 512 threads (8 waves 2x4, wave-tile 64x32), mfma_i32_16x16x64_i8.
// 3-buffer depth-2 pipeline, counted vmcnt(4); XOR swizzle per rule 21.
// Grid 256 = 1 block/CU.
// ---------------------------------------------------------------------------
__global__ __launch_bounds__(512, 1) void stdp_gemm_kernel(
    const u8* __restrict__ A, const u8* __restrict__ B,
    const float* __restrict__ W, float* __restrict__ C) {
  __shared__ u8 ldsA[3][128 * 128];   // 48 KB
  __shared__ u8 ldsB[3][128 * 128];   // 48 KB
  const int tid = threadIdx.x;
  const int lane = tid & 63, wave = tid >> 6;
  const int wm = wave >> 2, wn = wave & 3;     // 2 x 4 wave grid
  const int lr = lane & 15, lk = lane >> 4;

  // XCD-aware decode: 256 blocks -> 16x16 tiles, each XCD a 4x8 chunk
  const int bid = blockIdx.x;
  const int xcd = bid & 7, q = bid >> 3;       // q in [0,32)
  const int it = (xcd >> 1) * 4 + (q >> 3);    // 0..15
  const int jt = (xcd & 1) * 8 + (q & 7);      // 0..15
  const int i0 = it * 128, j0 = jt * 128;

  i32x4 acc[4][2];
#pragma unroll
  for (int m = 0; m < 4; ++m)
#pragma unroll
    for (int n = 0; n < 2; ++n) acc[m][n] = (i32x4){0, 0, 0, 0};

  // per stage: each thread-slot issues 2 A + 2 B gload_lds (16B = 16 i8)
  auto stage = [&](int buf, int kt) {
    const int k0 = kt * 128;
#pragma unroll
    for (int p = 0; p < 2; ++p) {
      int ch = p * 512 + tid;                  // 0..1023
      int r = ch >> 3, c = ch & 7;
      int csw = c ^ (r & 7);                   // inverse-swizzle the SOURCE
      __builtin_amdgcn_global_load_lds(
          (const AS1 void*)(A + (size_t)(i0 + r) * T_STEPS + k0 + csw * 16),
          (AS3 void*)((char*)&ldsA[buf][0] + (p * 512 + wave * 64) * 16),
          16, 0, 0);
    }
#pragma unroll
    for (int p = 0; p < 2; ++p) {
      int ch = p * 512 + tid;
      int r = ch >> 3, c = ch & 7;
      int csw = c ^ (r & 7);
      __builtin_amdgcn_global_load_lds(
          (const AS1 void*)(B + (size_t)(j0 + r) * T_STEPS + k0 + csw * 16),
          (AS3 void*)((char*)&ldsB[buf][0] + (p * 512 + wave * 64) * 16),
          16, 0, 0);
    }
  };

  stage(0, 0);
  stage(1, 1);                     // 8 loads in flight per wave

  const int NKT = T_STEPS / 128;   // 16
  int rb = 0;
  for (int kt = 0; kt < NKT; ++kt) {
    if (kt < NKT - 1) asm volatile("s_waitcnt vmcnt(4)" ::: "memory");
    else              asm volatile("s_waitcnt vmcnt(0)" ::: "memory");
    __builtin_amdgcn_s_barrier();   // tile kt fully in LDS for all waves
    asm volatile("" ::: "memory");

    if (kt + 2 < NKT) {             // overwrites buffer consumed at kt-1
      int sb = rb + 2; if (sb >= 3) sb -= 3;
      stage(sb, kt + 2);
    }

#pragma unroll
    for (int ks = 0; ks < 2; ++ks) {
      i32x4 af[4], bf[2];
#pragma unroll
      for (int m = 0; m < 4; ++m) {
        int row = wm * 64 + m * 16 + lr;
        int cg = (ks * 4 + lk) ^ (row & 7);    // swizzled read
        af[m] = *(const i32x4*)((const char*)&ldsA[rb][0] + row * 128 + cg * 16);
      }
#pragma unroll
      for (int n = 0; n < 2; ++n) {
        int row = wn * 32 + n * 16 + lr;
        int cg = (ks * 4 + lk) ^ (row & 7);
        bf[n] = *(const i32x4*)((const char*)&ldsB[rb][0] + row * 128 + cg * 16);
      }
      __builtin_amdgcn_s_setprio(1);
#pragma unroll
      for (int m = 0; m < 4; ++m)
#pragma unroll
        for (int n = 0; n < 2; ++n)
          acc[m][n] = __builtin_amdgcn_mfma_i32_16x16x64_i8(af[m], bf[n], acc[m][n], 0, 0, 0);
      __builtin_amdgcn_s_setprio(0);
    }
    rb = (rb == 2) ? 0 : rb + 1;
  }

  // epilogue: C = W + 1e-5 * acc  (C/D layout: col=lane&15, row=(lane>>4)*4+r)
#pragma unroll
  for (int m = 0; m < 4; ++m)
#pragma unroll
    for (int n = 0; n < 2; ++n) {
      int col = j0 + wn * 32 + n * 16 + lr;
#pragma unroll
      for (int r = 0; r < 4; ++r) {
        int row = i0 + wm * 64 + m * 16 + lk * 4 + r;
        size_t off = (size_t)row * NFEAT + col;
        C[off] = W[off] + OUTSCALE * (float)acc[m][n][r];
      }
    }
}

extern "C" void kernel_launch(void* const* d_in, const int* in_sizes, int n_in,
                              void* d_out, int out_size, void* d_ws, size_t ws_size,
                              hipStream_t stream) {
  const float* weight  = (const float*)d_in[0];
  const float* in_spk  = (const float*)d_in[1];
  const float* out_spk = (const float*)d_in[2];
  float* out = (float*)d_out;

  u8* kinT = (u8*)d_ws;                                   // 4 MB i8 [I][T]
  u8* outT = kinT + (size_t)T_STEPS * NFEAT;              // 4 MB i8 [O][T]

  prep_kernel<<<dim3(1280), 256, 0, stream>>>(in_spk, out_spk, kinT, outT);

  stdp_gemm_kernel<<<dim3(256), 512, 0, stream>>>(outT, kinT, weight, out);
}